// Round 5
// baseline (533.917 us; speedup 1.0000x reference)
//
#include <hip/hip_runtime.h>

// SphereHashGridBackground: ray-sphere + Instant-NGP hash grid encode with
// Morton-bucket counting sort (1 atomic pass) for gather locality.
// Level L: scale = 16*2^L - 1, res = 16<<L; levels 0..2 dense, 3..5 hashed.
constexpr unsigned kHashmapSize = 1u << 19;
constexpr float kSphereR = 500.0f;
constexpr int kNumBuckets = 1 << 15;   // 32x32x32 morton buckets

typedef float v4f __attribute__((ext_vector_type(4)));

__device__ __forceinline__ unsigned part1by2(unsigned x) {
    x &= 0x3FFu;
    x = (x | (x << 16)) & 0x030000FFu;
    x = (x | (x << 8))  & 0x0300F00Fu;
    x = (x | (x << 4))  & 0x030C30C3u;
    x = (x | (x << 2))  & 0x09249249u;
    return x;
}

__device__ __forceinline__ void ray_coords(const float* __restrict__ dirs,
                                           const float* __restrict__ orig,
                                           int n, float& cx, float& cy, float& cz) {
    float dx = dirs[3 * n + 0], dy = dirs[3 * n + 1], dz = dirs[3 * n + 2];
    float ox = orig[3 * n + 0], oy = orig[3 * n + 1], oz = orig[3 * n + 2];
    float b = 2.0f * ((ox * dx + oy * dy) + oz * dz);
    float c = ((ox * ox + oy * oy) + oz * oz) - kSphereR * kSphereR;
    float disc = b * b - 4.0f * c;
    float t = (-b + sqrtf(fmaxf(disc, 0.0f))) * 0.5f;
    float px = ox + t * dx, py = oy + t * dy, pz = oz + t * dz;
    cx = fminf(fmaxf((px + kSphereR) / (2.0f * kSphereR), 0.0f), 1.0f);
    cy = fminf(fmaxf((py + kSphereR) / (2.0f * kSphereR), 0.0f), 1.0f);
    cz = fminf(fmaxf((pz + kSphereR) / (2.0f * kSphereR), 0.0f), 1.0f);
}

__device__ __forceinline__ unsigned bucket_of(float cx, float cy, float cz) {
    unsigned qx = min(31u, (unsigned)(cx * 32.0f));
    unsigned qy = min(31u, (unsigned)(cy * 32.0f));
    unsigned qz = min(31u, (unsigned)(cz * 32.0f));
    return part1by2(qx) | (part1by2(qy) << 1) | (part1by2(qz) << 2);
}

// ---- P0: zero histogram (ws is poisoned before every launch)
__global__ __launch_bounds__(256)
void zero_hist_kernel(unsigned* __restrict__ hist) {
    int i = blockIdx.x * 256 + threadIdx.x;
    if (i < kNumBuckets) hist[i] = 0u;
}

// ---- P1: single atomic pass; record within-bucket rank
__global__ __launch_bounds__(256)
void rank_kernel(const float* __restrict__ dirs, const float* __restrict__ orig,
                 unsigned* __restrict__ hist, unsigned* __restrict__ aux, int n_rays) {
    int n = blockIdx.x * 256 + threadIdx.x;
    if (n >= n_rays) return;
    float cx, cy, cz;
    ray_coords(dirs, orig, n, cx, cy, cz);
    aux[n] = atomicAdd(&hist[bucket_of(cx, cy, cz)], 1u);
}

// ---- P2: exclusive prefix sum over 32768 buckets (single block, 1024 thr)
__global__ __launch_bounds__(1024)
void scan_kernel(unsigned* __restrict__ hist) {
    __shared__ unsigned sums[1024];
    const int t = threadIdx.x;
    constexpr int kPer = kNumBuckets / 1024; // 32
    unsigned local[kPer];
    unsigned s = 0;
#pragma unroll
    for (int i = 0; i < kPer; ++i) { local[i] = hist[t * kPer + i]; s += local[i]; }
    sums[t] = s;
    __syncthreads();
    for (int off = 1; off < 1024; off <<= 1) {
        unsigned v = (t >= off) ? sums[t - off] : 0u;
        __syncthreads();
        sums[t] += v;
        __syncthreads();
    }
    unsigned run = (t == 0) ? 0u : sums[t - 1]; // exclusive base
#pragma unroll
    for (int i = 0; i < kPer; ++i) { unsigned c = local[i]; hist[t * kPer + i] = run; run += c; }
}

// ---- P3: placement (no atomics): pos = base[key] + rank
__global__ __launch_bounds__(256)
void place_kernel(const float* __restrict__ dirs, const float* __restrict__ orig,
                  const unsigned* __restrict__ base, const unsigned* __restrict__ aux,
                  v4f* __restrict__ sorted, int n_rays) {
    int n = blockIdx.x * 256 + threadIdx.x;
    if (n >= n_rays) return;
    float cx, cy, cz;
    ray_coords(dirs, orig, n, cx, cy, cz);
    unsigned key = bucket_of(cx, cy, cz);
    unsigned pos = base[key] + aux[n];
    v4f v; v.x = cx; v.y = cy; v.z = cz; v.w = __uint_as_float((unsigned)n);
    sorted[pos] = v;
}

// ---- per-level index/frac computation (L resolved at compile time via unroll)
__device__ __forceinline__ void level_setup(int L, float cx, float cy, float cz,
                                            unsigned idx[8], float& fx, float& fy, float& fz) {
    const float sc = (float)(16 << L) - 1.0f;
    const unsigned res = 16u << L;
    const bool dense = (L < 3);
    float posx = cx * sc + 0.5f;
    float posy = cy * sc + 0.5f;
    float posz = cz * sc + 0.5f;
    float gx_f = floorf(posx), gy_f = floorf(posy), gz_f = floorf(posz);
    fx = posx - gx_f; fy = posy - gy_f; fz = posz - gz_f;
    unsigned gx = (unsigned)gx_f, gy = (unsigned)gy_f, gz = (unsigned)gz_f;
#pragma unroll
    for (int cr = 0; cr < 8; ++cr) {
        unsigned ii = (unsigned)(cr >> 2);
        unsigned jj = (unsigned)((cr >> 1) & 1);
        unsigned kk = (unsigned)(cr & 1);
        unsigned x = gx + ii, y = gy + jj, z = gz + kk;
        if (dense) {
            x = min(x, res - 1u);
            y = min(y, res - 1u);
            z = min(z, res - 1u);
            idx[cr] = x + y * res + z * res * res;
        } else {
            idx[cr] = (x * 1u ^ y * 2654435761u ^ z * 805459861u) & (kHashmapSize - 1u);
        }
    }
}

// ---- P4: encode over sorted rays, software-pipelined across levels
__global__ __launch_bounds__(256)
void encode_kernel(const v4f* __restrict__ sorted,
                   const v4f* __restrict__ table4,
                   float* __restrict__ out,
                   int n_rays, int nblocks) {
    // XCD-chunked swizzle: consecutive sorted chunks stay on one XCD's L2.
    int bid = blockIdx.x;
    int chunk = nblocks >> 3;
    int swz = (bid & 7) * chunk + (bid >> 3);
    int i = swz * 256 + (int)threadIdx.x;
    if (i >= n_rays) return;

    v4f s = __builtin_nontemporal_load(&sorted[i]);
    float cx = s.x, cy = s.y, cz = s.z;
    unsigned rayid = __float_as_uint(s.w);
    float* outp = out + (size_t)rayid * 24;

    // prologue: level 0
    unsigned idx[8];
    float fx, fy, fz;
    level_setup(0, cx, cy, cz, idx, fx, fy, fz);
    v4f fcur[8];
    {
        const v4f* __restrict__ tl = table4;
#pragma unroll
        for (int cr = 0; cr < 8; ++cr) fcur[cr] = tl[idx[cr]];
    }

#pragma unroll
    for (int L = 0; L < 6; ++L) {
        // issue next level's gathers before consuming current level
        v4f fnxt[8];
        float fxn = 0.f, fyn = 0.f, fzn = 0.f;
        if (L < 5) {
            unsigned idxn[8];
            level_setup(L + 1, cx, cy, cz, idxn, fxn, fyn, fzn);
            const v4f* __restrict__ tl = table4 + (size_t)(L + 1) * kHashmapSize;
#pragma unroll
            for (int cr = 0; cr < 8; ++cr) fnxt[cr] = tl[idxn[cr]];
        }

        float wx[2] = {1.0f - fx, fx};
        float wy[2] = {1.0f - fy, fy};
        float wz[2] = {1.0f - fz, fz};
        v4f acc; acc.x = 0.f; acc.y = 0.f; acc.z = 0.f; acc.w = 0.f;
#pragma unroll
        for (int cr = 0; cr < 8; ++cr) {
            float w = (wx[(cr >> 2) & 1] * wy[(cr >> 1) & 1]) * wz[cr & 1];
            acc += fcur[cr] * w;
        }
        __builtin_nontemporal_store(acc, (v4f*)(outp + L * 4));

        // rotate pipeline (SSA-renamed under full unroll)
        fx = fxn; fy = fyn; fz = fzn;
#pragma unroll
        for (int cr = 0; cr < 8; ++cr) fcur[cr] = fnxt[cr];
    }
}

extern "C" void kernel_launch(void* const* d_in, const int* in_sizes, int n_in,
                              void* d_out, int out_size, void* d_ws, size_t ws_size,
                              hipStream_t stream) {
    const float* dirs = (const float*)d_in[0];
    const float* orig = (const float*)d_in[1];
    const v4f* table4 = (const v4f*)d_in[2];
    float* out = (float*)d_out;

    int n_rays = in_sizes[0] / 3;

    // ws layout: sorted float4 [n_rays] | hist u32 [32768] | aux u32 [n_rays]
    v4f* sorted = (v4f*)d_ws;
    unsigned* hist = (unsigned*)((char*)d_ws + (size_t)n_rays * 16);
    unsigned* aux = hist + kNumBuckets;

    const int block = 256;
    int grid = (n_rays + block - 1) / block;

    zero_hist_kernel<<<(kNumBuckets + 255) / 256, block, 0, stream>>>(hist);
    rank_kernel<<<grid, block, 0, stream>>>(dirs, orig, hist, aux, n_rays);
    scan_kernel<<<1, 1024, 0, stream>>>(hist);
    place_kernel<<<grid, block, 0, stream>>>(dirs, orig, hist, aux, sorted, n_rays);
    encode_kernel<<<grid, block, 0, stream>>>(sorted, table4, out, n_rays, grid);
}